// Round 1
// baseline (1460.680 us; speedup 1.0000x reference)
//
#include <hip/hip_runtime.h>
#include <hip/hip_bf16.h>

#define NNODES 100000
#define NEDGES 1600000
#define NGRAPH 256
#define DIN 92
#define DOUT 64
#define BNEPS 1e-5f

// ---------------- init: deg = 1.0 (self-loop weight) ----------------
__global__ void k_init_deg(float* __restrict__ deg, int n) {
    int i = blockIdx.x * 256 + threadIdx.x;
    if (i < n) deg[i] = 1.0f;
}

// ---------------- deg[col[e]] += w[e] ----------------
__global__ void k_deg_scatter(const int* __restrict__ col, const float* __restrict__ w,
                              float* __restrict__ deg, int E) {
    int e = blockIdx.x * 256 + threadIdx.x;
    if (e < E) atomicAdd(&deg[col[e]], w[e]);
}

// ---------------- selfnorm[i] = 1/deg (dinv^2), norm[e] = dinv[row]*w*dinv[col] ----------------
__global__ void k_selfnorm(const float* __restrict__ deg, float* __restrict__ selfnorm, int n) {
    int i = blockIdx.x * 256 + threadIdx.x;
    if (i < n) {
        float d = deg[i];
        selfnorm[i] = (d > 0.0f) ? 1.0f / d : 0.0f;
    }
}

__global__ void k_norm(const int* __restrict__ row, const int* __restrict__ col,
                       const float* __restrict__ w, const float* __restrict__ deg,
                       float* __restrict__ norm, int E) {
    int e = blockIdx.x * 256 + threadIdx.x;
    if (e >= E) return;
    float dr = deg[row[e]];
    float dc = deg[col[e]];
    float a = (dr > 0.0f) ? rsqrtf(dr) : 0.0f;
    float c = (dc > 0.0f) ? rsqrtf(dc) : 0.0f;
    norm[e] = a * w[e] * c;
}

// ---------------- per-node GEMM + self-loop/bias epilogue ----------------
// H2 = Hin @ W  (Hin: [n,K], W: [K,64] row-major)
// AGG = b + selfnorm * H2   (self-loop message, bias)
template<int K>
__global__ __launch_bounds__(256) void k_gemm(const float* __restrict__ Hin,
                                              const float* __restrict__ W,
                                              const float* __restrict__ b,
                                              const float* __restrict__ selfnorm,
                                              float* __restrict__ H2,
                                              float* __restrict__ AGG, int n) {
    __shared__ float lW[K * 64];
    __shared__ float lX[16 * K];
    int tid = threadIdx.x;
    for (int idx = tid; idx < K * 64; idx += 256) lW[idx] = W[idx];
    int base = blockIdx.x * 16;
    for (int idx = tid; idx < 16 * K; idx += 256) {
        int nl = idx / K;
        int k  = idx - nl * K;
        int node = base + nl;
        lX[idx] = (node < n) ? Hin[(size_t)node * K + k] : 0.0f;
    }
    __syncthreads();
    int d = tid & 63, grp = tid >> 6;
    float bd = b[d];
    for (int i = 0; i < 4; ++i) {
        int nl = grp * 4 + i;
        int node = base + nl;
        if (node >= n) return;
        float acc = 0.0f;
        #pragma unroll 4
        for (int k = 0; k < K; ++k) acc += lX[nl * K + k] * lW[k * 64 + d];
        H2[(size_t)node * 64 + d] = acc;
        AGG[(size_t)node * 64 + d] = bd + selfnorm[node] * acc;
    }
}

// ---------------- edge scatter: AGG[col] += norm * H2[row], one wave per edge ----------------
__global__ __launch_bounds__(256) void k_scatter(const int* __restrict__ row,
                                                 const int* __restrict__ col,
                                                 const float* __restrict__ norm,
                                                 const float* __restrict__ H,
                                                 float* __restrict__ AGG, int E) {
    int wave = (blockIdx.x * 256 + threadIdx.x) >> 6;
    int d = threadIdx.x & 63;
    if (wave >= E) return;
    int r = row[wave];
    int c = col[wave];
    float nm = norm[wave];
    float v = nm * H[(size_t)r * 64 + d];
    atomicAdd(&AGG[(size_t)c * 64 + d], v);
}

// ---------------- BN stats: per-column sum and sumsq ----------------
__global__ __launch_bounds__(256) void k_stats(const float* __restrict__ AGG,
                                               float* __restrict__ stats, int n) {
    __shared__ float ls[256];
    __shared__ float lss[256];
    int d = threadIdx.x & 63, grp = threadIdx.x >> 6;
    float s = 0.0f, ss = 0.0f;
    for (int r = blockIdx.x * 4 + grp; r < n; r += gridDim.x * 4) {
        float v = AGG[(size_t)r * 64 + d];
        s += v;
        ss += v * v;
    }
    ls[threadIdx.x] = s;
    lss[threadIdx.x] = ss;
    __syncthreads();
    if (grp == 0) {
        s  = ls[d] + ls[64 + d] + ls[128 + d] + ls[192 + d];
        ss = lss[d] + lss[64 + d] + lss[128 + d] + lss[192 + d];
        atomicAdd(&stats[d], s);
        atomicAdd(&stats[64 + d], ss);
    }
}

// ---------------- BN apply + ReLU ----------------
__global__ __launch_bounds__(256) void k_bnapply(const float* __restrict__ AGG,
                                                 const float* __restrict__ stats,
                                                 const float* __restrict__ g,
                                                 const float* __restrict__ beta,
                                                 float* __restrict__ out,
                                                 int n, float inv_n) {
    size_t idx = (size_t)blockIdx.x * 256 + threadIdx.x;
    size_t total = (size_t)n * 64;
    if (idx >= total) return;
    int d = (int)(idx & 63);
    float mu  = stats[d] * inv_n;
    float var = stats[64 + d] * inv_n - mu * mu;
    float sc = g[d] * rsqrtf(var + BNEPS);
    float v = (AGG[idx] - mu) * sc + beta[d];
    out[idx] = fmaxf(v, 0.0f);
}

// ---------------- pool (mean by graph, batch sorted) + MLP head ----------------
__global__ __launch_bounds__(256) void k_pool_mlp(const float* __restrict__ H,
                                                  const int* __restrict__ batch, int n,
                                                  const float* __restrict__ Wp1,
                                                  const float* __restrict__ bp1,
                                                  const float* __restrict__ Wp2,
                                                  const float* __restrict__ bp2,
                                                  float* __restrict__ out) {
    int gidx = blockIdx.x;
    // lower_bound(batch, gidx) and lower_bound(batch, gidx+1)
    int lo = 0, hi = n;
    while (lo < hi) { int mid = (lo + hi) >> 1; if (batch[mid] < gidx) lo = mid + 1; else hi = mid; }
    int start = lo;
    lo = start; hi = n;
    while (lo < hi) { int mid = (lo + hi) >> 1; if (batch[mid] < gidx + 1) lo = mid + 1; else hi = mid; }
    int end = lo;

    int d = threadIdx.x & 63, grp = threadIdx.x >> 6;
    float s = 0.0f;
    for (int r = start + grp; r < end; r += 4) s += H[(size_t)r * 64 + d];
    __shared__ float ls[256];
    __shared__ float pooled[64];
    ls[threadIdx.x] = s;
    __syncthreads();
    if (grp == 0) {
        float cnt = (float)(end - start);
        float denom = fmaxf(cnt, 1.0f);
        pooled[d] = (ls[d] + ls[64 + d] + ls[128 + d] + ls[192 + d]) / denom;
    }
    __syncthreads();
    __shared__ float hidden[100];
    int j = threadIdx.x;
    if (j < 100) {
        float h = bp1[j];
        #pragma unroll 8
        for (int dd = 0; dd < 64; ++dd) h += pooled[dd] * Wp1[dd * 100 + j];
        hidden[j] = fmaxf(h, 0.0f);
    }
    __syncthreads();
    __shared__ float red[256];
    red[j] = (j < 100) ? hidden[j] * Wp2[j] : 0.0f;
    __syncthreads();
    for (int sft = 128; sft > 0; sft >>= 1) {
        if (j < sft) red[j] += red[j + sft];
        __syncthreads();
    }
    if (j == 0) out[gidx] = red[0] + bp2[0];
}

extern "C" void kernel_launch(void* const* d_in, const int* in_sizes, int n_in,
                              void* d_out, int out_size, void* d_ws, size_t ws_size,
                              hipStream_t stream) {
    const float* x    = (const float*)d_in[0];
    const int*   eidx = (const int*)d_in[1];
    const float* ew   = (const float*)d_in[2];
    const int*   batch= (const int*)d_in[3];
    const float* W0 = (const float*)d_in[4];  const float* b0 = (const float*)d_in[5];
    const float* g0 = (const float*)d_in[6];  const float* be0= (const float*)d_in[7];
    const float* W1 = (const float*)d_in[8];  const float* b1 = (const float*)d_in[9];
    const float* g1 = (const float*)d_in[10]; const float* be1= (const float*)d_in[11];
    const float* W2 = (const float*)d_in[12]; const float* b2 = (const float*)d_in[13];
    const float* g2 = (const float*)d_in[14]; const float* be2= (const float*)d_in[15];
    const float* Wp1= (const float*)d_in[16]; const float* bp1= (const float*)d_in[17];
    const float* Wp2= (const float*)d_in[18]; const float* bp2= (const float*)d_in[19];
    float* out = (float*)d_out;

    const int N = in_sizes[3];          // 100000
    const int E = in_sizes[2];          // 1600000
    const int* row = eidx;              // edge_index[0] = source
    const int* col = eidx + E;          // edge_index[1] = target

    // workspace layout
    size_t off = 0;
    auto alloc = [&](size_t bytes) {
        void* p = (char*)d_ws + off;
        off += (bytes + 255) & ~(size_t)255;
        return p;
    };
    float* deg      = (float*)alloc((size_t)N * 4);
    float* selfnorm = (float*)alloc((size_t)N * 4);
    float* norm     = (float*)alloc((size_t)E * 4);
    float* H2       = (float*)alloc((size_t)N * 64 * 4);
    float* AGG      = (float*)alloc((size_t)N * 64 * 4);
    float* H1       = (float*)alloc((size_t)N * 64 * 4);
    float* stats    = (float*)alloc(512);
    (void)ws_size;

    const int TB = 256;
    const int gN  = (N + TB - 1) / TB;
    const int gE  = (E + TB - 1) / TB;
    const int gNd = (N * 64 + TB - 1) / TB;      // N*64 = 6.4M elements
    const int gGemm = (N + 15) / 16;
    const int gScat = (E * 4 + TB - 1) / TB * 1; // wave per edge: E waves = E*64 threads
    const int gScatBlocks = (E + 3) / 4;         // 4 edges per 256-thread block
    const float inv_n = 1.0f / (float)N;

    // gcn_norm
    k_init_deg<<<gN, TB, 0, stream>>>(deg, N);
    k_deg_scatter<<<gE, TB, 0, stream>>>(col, ew, deg, E);
    k_selfnorm<<<gN, TB, 0, stream>>>(deg, selfnorm, N);
    k_norm<<<gE, TB, 0, stream>>>(row, col, ew, deg, norm, E);

    // layer 0
    k_gemm<92><<<gGemm, TB, 0, stream>>>(x, W0, b0, selfnorm, H2, AGG, N);
    k_scatter<<<gScatBlocks, TB, 0, stream>>>(row, col, norm, H2, AGG, E);
    hipMemsetAsync(stats, 0, 512, stream);
    k_stats<<<256, TB, 0, stream>>>(AGG, stats, N);
    k_bnapply<<<gNd, TB, 0, stream>>>(AGG, stats, g0, be0, H1, N, inv_n);

    // layer 1
    k_gemm<64><<<gGemm, TB, 0, stream>>>(H1, W1, b1, selfnorm, H2, AGG, N);
    k_scatter<<<gScatBlocks, TB, 0, stream>>>(row, col, norm, H2, AGG, E);
    hipMemsetAsync(stats, 0, 512, stream);
    k_stats<<<256, TB, 0, stream>>>(AGG, stats, N);
    k_bnapply<<<gNd, TB, 0, stream>>>(AGG, stats, g1, be1, H1, N, inv_n);

    // layer 2
    k_gemm<64><<<gGemm, TB, 0, stream>>>(H1, W2, b2, selfnorm, H2, AGG, N);
    k_scatter<<<gScatBlocks, TB, 0, stream>>>(row, col, norm, H2, AGG, E);
    hipMemsetAsync(stats, 0, 512, stream);
    k_stats<<<256, TB, 0, stream>>>(AGG, stats, N);
    k_bnapply<<<gNd, TB, 0, stream>>>(AGG, stats, g2, be2, H1, N, inv_n);

    // pool + MLP head
    k_pool_mlp<<<NGRAPH, TB, 0, stream>>>(H1, batch, N, Wp1, bp1, Wp2, bp2, out);

    (void)gScat; (void)n_in; (void)out_size;
}

// Round 2
// 983.353 us; speedup vs baseline: 1.4854x; 1.4854x over previous
//
#include <hip/hip_runtime.h>
#include <hip/hip_bf16.h>

#define NGRAPH 256
#define BNEPS 1e-5f

// ---------------- init: deg = 1.0 (self-loop weight) ----------------
__global__ void k_init_deg(float* __restrict__ deg, int n) {
    int i = blockIdx.x * 256 + threadIdx.x;
    if (i < n) deg[i] = 1.0f;
}

// ---------------- deg[col[e]] += w[e] ----------------
__global__ void k_deg_scatter(const int* __restrict__ col, const float* __restrict__ w,
                              float* __restrict__ deg, int E) {
    int e = blockIdx.x * 256 + threadIdx.x;
    if (e < E) atomicAdd(&deg[col[e]], w[e]);
}

// ---------------- selfnorm[i] = 1/deg ----------------
__global__ void k_selfnorm(const float* __restrict__ deg, float* __restrict__ selfnorm, int n) {
    int i = blockIdx.x * 256 + threadIdx.x;
    if (i < n) {
        float d = deg[i];
        selfnorm[i] = (d > 0.0f) ? 1.0f / d : 0.0f;
    }
}

// ---------------- CSR build: histogram of destinations ----------------
__global__ void k_hist(const int* __restrict__ col, int* __restrict__ cnt, int E) {
    int e = blockIdx.x * 256 + threadIdx.x;
    if (e < E) atomicAdd(&cnt[col[e]], 1);
}

// ---------------- scan stage 1: per-1024-block exclusive scan ----------------
__global__ __launch_bounds__(256) void k_scan1(const int* __restrict__ cnt, int* __restrict__ excl,
                                               int* __restrict__ bsum, int n) {
    __shared__ int p[256];
    int base = blockIdx.x * 1024 + threadIdx.x * 4;
    int v0 = (base + 0 < n) ? cnt[base + 0] : 0;
    int v1 = (base + 1 < n) ? cnt[base + 1] : 0;
    int v2 = (base + 2 < n) ? cnt[base + 2] : 0;
    int v3 = (base + 3 < n) ? cnt[base + 3] : 0;
    int tsum = v0 + v1 + v2 + v3;
    p[threadIdx.x] = tsum;
    __syncthreads();
    for (int o = 1; o < 256; o <<= 1) {
        int t = (threadIdx.x >= o) ? p[threadIdx.x - o] : 0;
        __syncthreads();
        p[threadIdx.x] += t;
        __syncthreads();
    }
    int texcl = p[threadIdx.x] - tsum;
    if (base + 0 < n) excl[base + 0] = texcl;
    if (base + 1 < n) excl[base + 1] = texcl + v0;
    if (base + 2 < n) excl[base + 2] = texcl + v0 + v1;
    if (base + 3 < n) excl[base + 3] = texcl + v0 + v1 + v2;
    if (threadIdx.x == 255) bsum[blockIdx.x] = p[255];
}

// ---------------- scan stage 2: exclusive scan of block sums (single block) ----------------
__global__ __launch_bounds__(256) void k_scan2(int* __restrict__ bsum, int nb) {
    __shared__ int p[256];
    int v = (threadIdx.x < nb) ? bsum[threadIdx.x] : 0;
    p[threadIdx.x] = v;
    __syncthreads();
    for (int o = 1; o < 256; o <<= 1) {
        int t = (threadIdx.x >= o) ? p[threadIdx.x - o] : 0;
        __syncthreads();
        p[threadIdx.x] += t;
        __syncthreads();
    }
    if (threadIdx.x < nb) bsum[threadIdx.x] = p[threadIdx.x] - v;
}

// ---------------- scan stage 3: add block offsets; set rowptr[n] ----------------
__global__ void k_scan3(int* __restrict__ rowptr, const int* __restrict__ bsum, int n, int E) {
    int i = blockIdx.x * 256 + threadIdx.x;
    if (i < n) rowptr[i] += bsum[i >> 10];
    if (i == 0) rowptr[n] = E;
}

// ---------------- CSR fill: edata[pos] = (src, norm) ----------------
__global__ void k_fill(const int* __restrict__ row, const int* __restrict__ col,
                       const float* __restrict__ w, const float* __restrict__ deg,
                       const int* __restrict__ rowptr, int* __restrict__ cursor,
                       float2* __restrict__ edata, int E) {
    int e = blockIdx.x * 256 + threadIdx.x;
    if (e >= E) return;
    int r = row[e];
    int c = col[e];
    float nm = rsqrtf(deg[r]) * w[e] * rsqrtf(deg[c]);
    int pos = rowptr[c] + atomicAdd(&cursor[c], 1);
    edata[pos] = make_float2(__int_as_float(r), nm);
}

// ---------------- per-node GEMM: H2 = Hin @ W ----------------
template<int K>
__global__ __launch_bounds__(256) void k_gemm(const float* __restrict__ Hin,
                                              const float* __restrict__ W,
                                              float* __restrict__ H2, int n) {
    __shared__ float lW[K * 64];
    __shared__ float lX[16 * K];
    int tid = threadIdx.x;
    for (int idx = tid; idx < K * 64; idx += 256) lW[idx] = W[idx];
    int base = blockIdx.x * 16;
    for (int idx = tid; idx < 16 * K; idx += 256) {
        int nl = idx / K;
        int k  = idx - nl * K;
        int node = base + nl;
        lX[idx] = (node < n) ? Hin[(size_t)node * K + k] : 0.0f;
    }
    __syncthreads();
    int d = tid & 63, grp = tid >> 6;
    for (int i = 0; i < 4; ++i) {
        int nl = grp * 4 + i;
        int node = base + nl;
        if (node >= n) return;
        float acc = 0.0f;
        #pragma unroll 4
        for (int k = 0; k < K; ++k) acc += lX[nl * K + k] * lW[k * 64 + d];
        H2[(size_t)node * 64 + d] = acc;
    }
}

// ---------------- gather aggregation: one wave per destination node ----------------
// AGG[i] = b + selfnorm[i]*H[i] + sum_e norm_e * H[src_e]
__global__ __launch_bounds__(256) void k_gather(const int* __restrict__ rowptr,
                                                const float2* __restrict__ edata,
                                                const float* __restrict__ H,
                                                const float* __restrict__ b,
                                                const float* __restrict__ selfnorm,
                                                float* __restrict__ AGG, int n) {
    int node = (blockIdx.x * 256 + threadIdx.x) >> 6;
    int d = threadIdx.x & 63;
    if (node >= n) return;
    int s = rowptr[node], e = rowptr[node + 1];
    float acc = b[d] + selfnorm[node] * H[(size_t)node * 64 + d];
    for (int p = s; p < e; ++p) {
        float2 ed = edata[p];
        acc += ed.y * H[(size_t)__float_as_int(ed.x) * 64 + d];
    }
    AGG[(size_t)node * 64 + d] = acc;
}

// ---------------- BN stats: per-column sum and sumsq ----------------
__global__ __launch_bounds__(256) void k_stats(const float* __restrict__ AGG,
                                               float* __restrict__ stats, int n) {
    __shared__ float ls[256];
    __shared__ float lss[256];
    int d = threadIdx.x & 63, grp = threadIdx.x >> 6;
    float s = 0.0f, ss = 0.0f;
    for (int r = blockIdx.x * 4 + grp; r < n; r += gridDim.x * 4) {
        float v = AGG[(size_t)r * 64 + d];
        s += v;
        ss += v * v;
    }
    ls[threadIdx.x] = s;
    lss[threadIdx.x] = ss;
    __syncthreads();
    if (grp == 0) {
        s  = ls[d] + ls[64 + d] + ls[128 + d] + ls[192 + d];
        ss = lss[d] + lss[64 + d] + lss[128 + d] + lss[192 + d];
        atomicAdd(&stats[d], s);
        atomicAdd(&stats[64 + d], ss);
    }
}

// ---------------- BN apply + ReLU (float4) ----------------
__global__ __launch_bounds__(256) void k_bnapply(const float4* __restrict__ AGG4,
                                                 const float* __restrict__ stats,
                                                 const float* __restrict__ g,
                                                 const float* __restrict__ beta,
                                                 float4* __restrict__ out4,
                                                 int n, float inv_n) {
    size_t idx = (size_t)blockIdx.x * 256 + threadIdx.x;
    size_t total = (size_t)n * 16;
    if (idx >= total) return;
    int d0 = (int)((idx & 15) * 4);
    float4 v = AGG4[idx];
    float r[4] = {v.x, v.y, v.z, v.w};
    #pragma unroll
    for (int j = 0; j < 4; ++j) {
        int d = d0 + j;
        float mu  = stats[d] * inv_n;
        float var = stats[64 + d] * inv_n - mu * mu;
        float sc = g[d] * rsqrtf(var + BNEPS);
        r[j] = fmaxf((r[j] - mu) * sc + beta[d], 0.0f);
    }
    out4[idx] = make_float4(r[0], r[1], r[2], r[3]);
}

// ---------------- pool (mean by graph, batch sorted) + MLP head ----------------
__global__ __launch_bounds__(256) void k_pool_mlp(const float* __restrict__ H,
                                                  const int* __restrict__ batch, int n,
                                                  const float* __restrict__ Wp1,
                                                  const float* __restrict__ bp1,
                                                  const float* __restrict__ Wp2,
                                                  const float* __restrict__ bp2,
                                                  float* __restrict__ out) {
    int gidx = blockIdx.x;
    int lo = 0, hi = n;
    while (lo < hi) { int mid = (lo + hi) >> 1; if (batch[mid] < gidx) lo = mid + 1; else hi = mid; }
    int start = lo;
    lo = start; hi = n;
    while (lo < hi) { int mid = (lo + hi) >> 1; if (batch[mid] < gidx + 1) lo = mid + 1; else hi = mid; }
    int end = lo;

    int d = threadIdx.x & 63, grp = threadIdx.x >> 6;
    float s = 0.0f;
    for (int r = start + grp; r < end; r += 4) s += H[(size_t)r * 64 + d];
    __shared__ float ls[256];
    __shared__ float pooled[64];
    ls[threadIdx.x] = s;
    __syncthreads();
    if (grp == 0) {
        float cnt = (float)(end - start);
        float denom = fmaxf(cnt, 1.0f);
        pooled[d] = (ls[d] + ls[64 + d] + ls[128 + d] + ls[192 + d]) / denom;
    }
    __syncthreads();
    __shared__ float hidden[100];
    int j = threadIdx.x;
    if (j < 100) {
        float h = bp1[j];
        #pragma unroll 8
        for (int dd = 0; dd < 64; ++dd) h += pooled[dd] * Wp1[dd * 100 + j];
        hidden[j] = fmaxf(h, 0.0f);
    }
    __syncthreads();
    __shared__ float red[256];
    red[j] = (j < 100) ? hidden[j] * Wp2[j] : 0.0f;
    __syncthreads();
    for (int sft = 128; sft > 0; sft >>= 1) {
        if (j < sft) red[j] += red[j + sft];
        __syncthreads();
    }
    if (j == 0) out[gidx] = red[0] + bp2[0];
}

extern "C" void kernel_launch(void* const* d_in, const int* in_sizes, int n_in,
                              void* d_out, int out_size, void* d_ws, size_t ws_size,
                              hipStream_t stream) {
    const float* x    = (const float*)d_in[0];
    const int*   eidx = (const int*)d_in[1];
    const float* ew   = (const float*)d_in[2];
    const int*   batch= (const int*)d_in[3];
    const float* W0 = (const float*)d_in[4];  const float* b0 = (const float*)d_in[5];
    const float* g0 = (const float*)d_in[6];  const float* be0= (const float*)d_in[7];
    const float* W1 = (const float*)d_in[8];  const float* b1 = (const float*)d_in[9];
    const float* g1 = (const float*)d_in[10]; const float* be1= (const float*)d_in[11];
    const float* W2 = (const float*)d_in[12]; const float* b2 = (const float*)d_in[13];
    const float* g2 = (const float*)d_in[14]; const float* be2= (const float*)d_in[15];
    const float* Wp1= (const float*)d_in[16]; const float* bp1= (const float*)d_in[17];
    const float* Wp2= (const float*)d_in[18]; const float* bp2= (const float*)d_in[19];
    float* out = (float*)d_out;

    const int N = in_sizes[3];
    const int E = in_sizes[2];
    const int* row = eidx;          // sources
    const int* col = eidx + E;      // destinations

    // workspace layout
    size_t off = 0;
    auto alloc = [&](size_t bytes) {
        void* p = (char*)d_ws + off;
        off += (bytes + 255) & ~(size_t)255;
        return p;
    };
    float*  deg      = (float*)alloc((size_t)N * 4);
    float*  selfnorm = (float*)alloc((size_t)N * 4);
    int*    cnt      = (int*)alloc((size_t)N * 4);      // reused as cursor after scan
    int*    rowptr   = (int*)alloc((size_t)(N + 1) * 4);
    int*    bsum     = (int*)alloc(1024);
    float2* edata    = (float2*)alloc((size_t)E * 8);
    float*  H2       = (float*)alloc((size_t)N * 64 * 4);
    float*  AGG      = (float*)alloc((size_t)N * 64 * 4);
    float*  H1       = (float*)alloc((size_t)N * 64 * 4);
    float*  stats    = (float*)alloc(512);
    (void)ws_size;

    const int TB = 256;
    const int gN   = (N + TB - 1) / TB;
    const int gE   = (E + TB - 1) / TB;
    const int gNd4 = (N * 16 + TB - 1) / TB;
    const int gGemm = (N + 15) / 16;
    const int gGath = (N * 64 + TB - 1) / TB;   // 1 wave per node, 4 nodes/block
    const int nbScan = (N + 1023) / 1024;
    const float inv_n = 1.0f / (float)N;

    // ---- gcn_norm + CSR build ----
    k_init_deg<<<gN, TB, 0, stream>>>(deg, N);
    k_deg_scatter<<<gE, TB, 0, stream>>>(col, ew, deg, E);
    k_selfnorm<<<gN, TB, 0, stream>>>(deg, selfnorm, N);

    hipMemsetAsync(cnt, 0, (size_t)N * 4, stream);
    k_hist<<<gE, TB, 0, stream>>>(col, cnt, E);
    k_scan1<<<nbScan, TB, 0, stream>>>(cnt, rowptr, bsum, N);
    k_scan2<<<1, TB, 0, stream>>>(bsum, nbScan);
    k_scan3<<<gN, TB, 0, stream>>>(rowptr, bsum, N, E);
    hipMemsetAsync(cnt, 0, (size_t)N * 4, stream);   // cursor
    k_fill<<<gE, TB, 0, stream>>>(row, col, ew, deg, rowptr, cnt, edata, E);

    // ---- layer 0 ----
    k_gemm<92><<<gGemm, TB, 0, stream>>>(x, W0, H2, N);
    k_gather<<<gGath, TB, 0, stream>>>(rowptr, edata, H2, b0, selfnorm, AGG, N);
    hipMemsetAsync(stats, 0, 512, stream);
    k_stats<<<256, TB, 0, stream>>>(AGG, stats, N);
    k_bnapply<<<gNd4, TB, 0, stream>>>((const float4*)AGG, stats, g0, be0, (float4*)H1, N, inv_n);

    // ---- layer 1 ----
    k_gemm<64><<<gGemm, TB, 0, stream>>>(H1, W1, H2, N);
    k_gather<<<gGath, TB, 0, stream>>>(rowptr, edata, H2, b1, selfnorm, AGG, N);
    hipMemsetAsync(stats, 0, 512, stream);
    k_stats<<<256, TB, 0, stream>>>(AGG, stats, N);
    k_bnapply<<<gNd4, TB, 0, stream>>>((const float4*)AGG, stats, g1, be1, (float4*)H1, N, inv_n);

    // ---- layer 2 ----
    k_gemm<64><<<gGemm, TB, 0, stream>>>(H1, W2, H2, N);
    k_gather<<<gGath, TB, 0, stream>>>(rowptr, edata, H2, b2, selfnorm, AGG, N);
    hipMemsetAsync(stats, 0, 512, stream);
    k_stats<<<256, TB, 0, stream>>>(AGG, stats, N);
    k_bnapply<<<gNd4, TB, 0, stream>>>((const float4*)AGG, stats, g2, be2, (float4*)H1, N, inv_n);

    // ---- pool + MLP head ----
    k_pool_mlp<<<NGRAPH, TB, 0, stream>>>(H1, batch, N, Wp1, bp1, Wp2, bp2, out);

    (void)n_in; (void)out_size;
}

// Round 3
// 785.894 us; speedup vs baseline: 1.8586x; 1.2513x over previous
//
#include <hip/hip_runtime.h>
#include <hip/hip_bf16.h>

#define NGRAPH 256
#define BNEPS 1e-5f

// ---------------- init: deg = 1.0 (self-loop weight) ----------------
__global__ void k_init_deg(float* __restrict__ deg, int n) {
    int i = blockIdx.x * 256 + threadIdx.x;
    if (i < n) deg[i] = 1.0f;
}

// ---------------- deg[col[e]] += w[e] ----------------
__global__ void k_deg_scatter(const int* __restrict__ col, const float* __restrict__ w,
                              float* __restrict__ deg, int E) {
    int e = blockIdx.x * 256 + threadIdx.x;
    if (e < E) atomicAdd(&deg[col[e]], w[e]);
}

// ---------------- selfnorm[i] = 1/deg ----------------
__global__ void k_selfnorm(const float* __restrict__ deg, float* __restrict__ selfnorm, int n) {
    int i = blockIdx.x * 256 + threadIdx.x;
    if (i < n) {
        float d = deg[i];
        selfnorm[i] = (d > 0.0f) ? 1.0f / d : 0.0f;
    }
}

// ---------------- CSR build: histogram of destinations ----------------
__global__ void k_hist(const int* __restrict__ col, int* __restrict__ cnt, int E) {
    int e = blockIdx.x * 256 + threadIdx.x;
    if (e < E) atomicAdd(&cnt[col[e]], 1);
}

// ---------------- scan stage 1: per-1024-block exclusive scan of PADDED counts ----------------
// pad each node's segment to a multiple of 8 edges (for aligned float4 gather loads)
__global__ __launch_bounds__(256) void k_scan1(const int* __restrict__ cnt, int* __restrict__ excl,
                                               int* __restrict__ bsum, int n) {
    __shared__ int p[256];
    int base = blockIdx.x * 1024 + threadIdx.x * 4;
    int v0 = (base + 0 < n) ? ((cnt[base + 0] + 7) & ~7) : 0;
    int v1 = (base + 1 < n) ? ((cnt[base + 1] + 7) & ~7) : 0;
    int v2 = (base + 2 < n) ? ((cnt[base + 2] + 7) & ~7) : 0;
    int v3 = (base + 3 < n) ? ((cnt[base + 3] + 7) & ~7) : 0;
    int tsum = v0 + v1 + v2 + v3;
    p[threadIdx.x] = tsum;
    __syncthreads();
    for (int o = 1; o < 256; o <<= 1) {
        int t = (threadIdx.x >= o) ? p[threadIdx.x - o] : 0;
        __syncthreads();
        p[threadIdx.x] += t;
        __syncthreads();
    }
    int texcl = p[threadIdx.x] - tsum;
    if (base + 0 < n) excl[base + 0] = texcl;
    if (base + 1 < n) excl[base + 1] = texcl + v0;
    if (base + 2 < n) excl[base + 2] = texcl + v0 + v1;
    if (base + 3 < n) excl[base + 3] = texcl + v0 + v1 + v2;
    if (threadIdx.x == 255) bsum[blockIdx.x] = p[255];
}

// ---------------- scan stage 2: exclusive scan of block sums; write total to rowptr[n] ----------------
__global__ __launch_bounds__(256) void k_scan2(int* __restrict__ bsum, int nb, int* __restrict__ totalOut) {
    __shared__ int p[256];
    int v = (threadIdx.x < nb) ? bsum[threadIdx.x] : 0;
    p[threadIdx.x] = v;
    __syncthreads();
    for (int o = 1; o < 256; o <<= 1) {
        int t = (threadIdx.x >= o) ? p[threadIdx.x - o] : 0;
        __syncthreads();
        p[threadIdx.x] += t;
        __syncthreads();
    }
    if (threadIdx.x == nb - 1) totalOut[0] = p[threadIdx.x];
    if (threadIdx.x < nb) bsum[threadIdx.x] = p[threadIdx.x] - v;
}

// ---------------- scan stage 3: add block offsets ----------------
__global__ void k_scan3(int* __restrict__ rowptr, const int* __restrict__ bsum, int n) {
    int i = blockIdx.x * 256 + threadIdx.x;
    if (i < n) rowptr[i] += bsum[i >> 10];
}

// ---------------- CSR fill: edata[pos] = (src, norm); padded slots stay (0,0) ----------------
__global__ void k_fill(const int* __restrict__ row, const int* __restrict__ col,
                       const float* __restrict__ w, const float* __restrict__ deg,
                       const int* __restrict__ rowptr, int* __restrict__ cursor,
                       float2* __restrict__ edata, int E) {
    int e = blockIdx.x * 256 + threadIdx.x;
    if (e >= E) return;
    int r = row[e];
    int c = col[e];
    float nm = rsqrtf(deg[r]) * w[e] * rsqrtf(deg[c]);
    int pos = rowptr[c] + atomicAdd(&cursor[c], 1);
    edata[pos] = make_float2(__int_as_float(r), nm);
}

// ---------------- per-node GEMM, W column in registers, x rows as uniform broadcasts ----------------
// H2 = Hin @ W  (Hin: [n,K], W: [K,64] row-major). One wave handles NPW nodes; lane = output dim.
template<int K, int NPW>
__global__ __launch_bounds__(256) void k_gemm(const float* __restrict__ Hin,
                                              const float* __restrict__ W,
                                              float* __restrict__ H2, int n) {
    int wave = (blockIdx.x * 256 + threadIdx.x) >> 6;
    int d = threadIdx.x & 63;
    float w[K];
    #pragma unroll
    for (int k = 0; k < K; ++k) w[k] = W[k * 64 + d];   // coalesced, L2-hot
    int base = wave * NPW;
    #pragma unroll
    for (int i = 0; i < NPW; ++i) {
        int node = base + i;
        bool ok = (node < n);
        const float* xr = Hin + (size_t)(ok ? node : 0) * K;
        float acc = 0.0f;
        #pragma unroll
        for (int kq = 0; kq < K / 4; ++kq) {
            float4 xq = *(const float4*)(xr + 4 * kq);  // wave-uniform broadcast
            acc = fmaf(xq.x, w[4 * kq + 0], acc);
            acc = fmaf(xq.y, w[4 * kq + 1], acc);
            acc = fmaf(xq.z, w[4 * kq + 2], acc);
            acc = fmaf(xq.w, w[4 * kq + 3], acc);
        }
        if (ok) H2[(size_t)node * 64 + d] = acc;
    }
}

// ---------------- gather aggregation: one wave per destination node, 8 edges per iter ----------------
// AGG[i] = b + selfnorm[i]*H[i] + sum_e norm_e * H[src_e]   (segments padded to 8, pads are (0,0))
__global__ __launch_bounds__(256) void k_gather(const int* __restrict__ rowptr,
                                                const float2* __restrict__ edata,
                                                const float* __restrict__ H,
                                                const float* __restrict__ b,
                                                const float* __restrict__ selfnorm,
                                                float* __restrict__ AGG, int n) {
    int node = (blockIdx.x * 256 + threadIdx.x) >> 6;
    int d = threadIdx.x & 63;
    if (node >= n) return;
    int s = rowptr[node], e = rowptr[node + 1];
    float acc = b[d] + selfnorm[node] * H[(size_t)node * 64 + d];
    for (int p = s; p < e; p += 8) {
        float4 q0 = *(const float4*)&edata[p];
        float4 q1 = *(const float4*)&edata[p + 2];
        float4 q2 = *(const float4*)&edata[p + 4];
        float4 q3 = *(const float4*)&edata[p + 6];
        float a0 = H[(size_t)__float_as_int(q0.x) * 64 + d];
        float a1 = H[(size_t)__float_as_int(q0.z) * 64 + d];
        float a2 = H[(size_t)__float_as_int(q1.x) * 64 + d];
        float a3 = H[(size_t)__float_as_int(q1.z) * 64 + d];
        float a4 = H[(size_t)__float_as_int(q2.x) * 64 + d];
        float a5 = H[(size_t)__float_as_int(q2.z) * 64 + d];
        float a6 = H[(size_t)__float_as_int(q3.x) * 64 + d];
        float a7 = H[(size_t)__float_as_int(q3.z) * 64 + d];
        acc = fmaf(q0.y, a0, acc);
        acc = fmaf(q0.w, a1, acc);
        acc = fmaf(q1.y, a2, acc);
        acc = fmaf(q1.w, a3, acc);
        acc = fmaf(q2.y, a4, acc);
        acc = fmaf(q2.w, a5, acc);
        acc = fmaf(q3.y, a6, acc);
        acc = fmaf(q3.w, a7, acc);
    }
    AGG[(size_t)node * 64 + d] = acc;
}

// ---------------- BN stats: per-column sum and sumsq ----------------
__global__ __launch_bounds__(256) void k_stats(const float* __restrict__ AGG,
                                               float* __restrict__ stats, int n) {
    __shared__ float ls[256];
    __shared__ float lss[256];
    int d = threadIdx.x & 63, grp = threadIdx.x >> 6;
    float s = 0.0f, ss = 0.0f;
    for (int r = blockIdx.x * 4 + grp; r < n; r += gridDim.x * 4) {
        float v = AGG[(size_t)r * 64 + d];
        s += v;
        ss += v * v;
    }
    ls[threadIdx.x] = s;
    lss[threadIdx.x] = ss;
    __syncthreads();
    if (grp == 0) {
        s  = ls[d] + ls[64 + d] + ls[128 + d] + ls[192 + d];
        ss = lss[d] + lss[64 + d] + lss[128 + d] + lss[192 + d];
        atomicAdd(&stats[d], s);
        atomicAdd(&stats[64 + d], ss);
    }
}

// ---------------- BN apply + ReLU (float4) ----------------
__global__ __launch_bounds__(256) void k_bnapply(const float4* __restrict__ AGG4,
                                                 const float* __restrict__ stats,
                                                 const float* __restrict__ g,
                                                 const float* __restrict__ beta,
                                                 float4* __restrict__ out4,
                                                 int n, float inv_n) {
    size_t idx = (size_t)blockIdx.x * 256 + threadIdx.x;
    size_t total = (size_t)n * 16;
    if (idx >= total) return;
    int d0 = (int)((idx & 15) * 4);
    float4 v = AGG4[idx];
    float r[4] = {v.x, v.y, v.z, v.w};
    #pragma unroll
    for (int j = 0; j < 4; ++j) {
        int d = d0 + j;
        float mu  = stats[d] * inv_n;
        float var = stats[64 + d] * inv_n - mu * mu;
        float sc = g[d] * rsqrtf(var + BNEPS);
        r[j] = fmaxf((r[j] - mu) * sc + beta[d], 0.0f);
    }
    out4[idx] = make_float4(r[0], r[1], r[2], r[3]);
}

// ---------------- pool (mean by graph, batch sorted) + MLP head ----------------
__global__ __launch_bounds__(256) void k_pool_mlp(const float* __restrict__ H,
                                                  const int* __restrict__ batch, int n,
                                                  const float* __restrict__ Wp1,
                                                  const float* __restrict__ bp1,
                                                  const float* __restrict__ Wp2,
                                                  const float* __restrict__ bp2,
                                                  float* __restrict__ out) {
    int gidx = blockIdx.x;
    int lo = 0, hi = n;
    while (lo < hi) { int mid = (lo + hi) >> 1; if (batch[mid] < gidx) lo = mid + 1; else hi = mid; }
    int start = lo;
    lo = start; hi = n;
    while (lo < hi) { int mid = (lo + hi) >> 1; if (batch[mid] < gidx + 1) lo = mid + 1; else hi = mid; }
    int end = lo;

    int d = threadIdx.x & 63, grp = threadIdx.x >> 6;
    float s = 0.0f;
    for (int r = start + grp; r < end; r += 4) s += H[(size_t)r * 64 + d];
    __shared__ float ls[256];
    __shared__ float pooled[64];
    ls[threadIdx.x] = s;
    __syncthreads();
    if (grp == 0) {
        float cnt = (float)(end - start);
        float denom = fmaxf(cnt, 1.0f);
        pooled[d] = (ls[d] + ls[64 + d] + ls[128 + d] + ls[192 + d]) / denom;
    }
    __syncthreads();
    __shared__ float hidden[100];
    int j = threadIdx.x;
    if (j < 100) {
        float h = bp1[j];
        #pragma unroll 8
        for (int dd = 0; dd < 64; ++dd) h += pooled[dd] * Wp1[dd * 100 + j];
        hidden[j] = fmaxf(h, 0.0f);
    }
    __syncthreads();
    __shared__ float red[256];
    red[j] = (j < 100) ? hidden[j] * Wp2[j] : 0.0f;
    __syncthreads();
    for (int sft = 128; sft > 0; sft >>= 1) {
        if (j < sft) red[j] += red[j + sft];
        __syncthreads();
    }
    if (j == 0) out[gidx] = red[0] + bp2[0];
}

extern "C" void kernel_launch(void* const* d_in, const int* in_sizes, int n_in,
                              void* d_out, int out_size, void* d_ws, size_t ws_size,
                              hipStream_t stream) {
    const float* x    = (const float*)d_in[0];
    const int*   eidx = (const int*)d_in[1];
    const float* ew   = (const float*)d_in[2];
    const int*   batch= (const int*)d_in[3];
    const float* W0 = (const float*)d_in[4];  const float* b0 = (const float*)d_in[5];
    const float* g0 = (const float*)d_in[6];  const float* be0= (const float*)d_in[7];
    const float* W1 = (const float*)d_in[8];  const float* b1 = (const float*)d_in[9];
    const float* g1 = (const float*)d_in[10]; const float* be1= (const float*)d_in[11];
    const float* W2 = (const float*)d_in[12]; const float* b2 = (const float*)d_in[13];
    const float* g2 = (const float*)d_in[14]; const float* be2= (const float*)d_in[15];
    const float* Wp1= (const float*)d_in[16]; const float* bp1= (const float*)d_in[17];
    const float* Wp2= (const float*)d_in[18]; const float* bp2= (const float*)d_in[19];
    float* out = (float*)d_out;

    const int N = in_sizes[3];
    const int E = in_sizes[2];
    const int* row = eidx;          // sources
    const int* col = eidx + E;      // destinations

    // workspace layout
    size_t off = 0;
    auto alloc = [&](size_t bytes) {
        void* p = (char*)d_ws + off;
        off += (bytes + 255) & ~(size_t)255;
        return p;
    };
    const size_t EPAD = (size_t)E + 7 * (size_t)N;   // upper bound on padded edge count
    float*  deg      = (float*)alloc((size_t)N * 4);
    float*  selfnorm = (float*)alloc((size_t)N * 4);
    int*    cnt      = (int*)alloc((size_t)N * 4);      // reused as cursor after scan
    int*    rowptr   = (int*)alloc((size_t)(N + 1) * 4);
    int*    bsum     = (int*)alloc(1024);
    float2* edata    = (float2*)alloc(EPAD * 8);
    float*  H2       = (float*)alloc((size_t)N * 64 * 4);
    float*  AGG      = (float*)alloc((size_t)N * 64 * 4);
    float*  H1       = (float*)alloc((size_t)N * 64 * 4);
    float*  stats    = (float*)alloc(512);
    (void)ws_size;

    const int TB = 256;
    const int gN    = (N + TB - 1) / TB;
    const int gE    = (E + TB - 1) / TB;
    const int gNd4  = (N * 16 + TB - 1) / TB;
    const int gGemm0 = (N + 31) / 32;   // NPW=8,  4 waves/block
    const int gGemm1 = (N + 63) / 64;   // NPW=16, 4 waves/block
    const int gGath = (N + 3) / 4;      // 1 wave per node
    const int nbScan = (N + 1023) / 1024;
    const float inv_n = 1.0f / (float)N;

    // ---- gcn_norm + padded CSR build ----
    k_init_deg<<<gN, TB, 0, stream>>>(deg, N);
    k_deg_scatter<<<gE, TB, 0, stream>>>(col, ew, deg, E);
    k_selfnorm<<<gN, TB, 0, stream>>>(deg, selfnorm, N);

    hipMemsetAsync(cnt, 0, (size_t)N * 4, stream);
    k_hist<<<gE, TB, 0, stream>>>(col, cnt, E);
    k_scan1<<<nbScan, TB, 0, stream>>>(cnt, rowptr, bsum, N);
    k_scan2<<<1, TB, 0, stream>>>(bsum, nbScan, rowptr + N);
    k_scan3<<<gN, TB, 0, stream>>>(rowptr, bsum, N);
    hipMemsetAsync(cnt, 0, (size_t)N * 4, stream);     // cursor
    hipMemsetAsync(edata, 0, EPAD * 8, stream);        // pad slots -> (src=0, nrm=0)
    k_fill<<<gE, TB, 0, stream>>>(row, col, ew, deg, rowptr, cnt, edata, E);

    // ---- layer 0 ----
    k_gemm<92, 8><<<gGemm0, TB, 0, stream>>>(x, W0, H2, N);
    k_gather<<<gGath, TB, 0, stream>>>(rowptr, edata, H2, b0, selfnorm, AGG, N);
    hipMemsetAsync(stats, 0, 512, stream);
    k_stats<<<256, TB, 0, stream>>>(AGG, stats, N);
    k_bnapply<<<gNd4, TB, 0, stream>>>((const float4*)AGG, stats, g0, be0, (float4*)H1, N, inv_n);

    // ---- layer 1 ----
    k_gemm<64, 16><<<gGemm1, TB, 0, stream>>>(H1, W1, H2, N);
    k_gather<<<gGath, TB, 0, stream>>>(rowptr, edata, H2, b1, selfnorm, AGG, N);
    hipMemsetAsync(stats, 0, 512, stream);
    k_stats<<<256, TB, 0, stream>>>(AGG, stats, N);
    k_bnapply<<<gNd4, TB, 0, stream>>>((const float4*)AGG, stats, g1, be1, (float4*)H1, N, inv_n);

    // ---- layer 2 ----
    k_gemm<64, 16><<<gGemm1, TB, 0, stream>>>(H1, W2, H2, N);
    k_gather<<<gGath, TB, 0, stream>>>(rowptr, edata, H2, b2, selfnorm, AGG, N);
    hipMemsetAsync(stats, 0, 512, stream);
    k_stats<<<256, TB, 0, stream>>>(AGG, stats, N);
    k_bnapply<<<gNd4, TB, 0, stream>>>((const float4*)AGG, stats, g2, be2, (float4*)H1, N, inv_n);

    // ---- pool + MLP head ----
    k_pool_mlp<<<NGRAPH, TB, 0, stream>>>(H1, batch, N, Wp1, bp1, Wp2, bp2, out);

    (void)n_in; (void)out_size;
}

// Round 4
// 660.942 us; speedup vs baseline: 2.2100x; 1.1891x over previous
//
#include <hip/hip_runtime.h>
#include <hip/hip_bf16.h>

#define NGRAPH 256
#define BNEPS 1e-5f

// ---------------- init: deg = 1.0 (self-loop weight) ----------------
__global__ void k_init_deg(float* __restrict__ deg, int n) {
    int i = blockIdx.x * 256 + threadIdx.x;
    if (i < n) deg[i] = 1.0f;
}

// ---------------- deg[col[e]] += w[e] ----------------
__global__ void k_deg_scatter(const int* __restrict__ col, const float* __restrict__ w,
                              float* __restrict__ deg, int E) {
    int e = blockIdx.x * 256 + threadIdx.x;
    if (e < E) atomicAdd(&deg[col[e]], w[e]);
}

// ---------------- selfnorm[i] = 1/deg ----------------
__global__ void k_selfnorm(const float* __restrict__ deg, float* __restrict__ selfnorm, int n) {
    int i = blockIdx.x * 256 + threadIdx.x;
    if (i < n) {
        float d = deg[i];
        selfnorm[i] = (d > 0.0f) ? 1.0f / d : 0.0f;
    }
}

// ---------------- CSR build: histogram of destinations ----------------
__global__ void k_hist(const int* __restrict__ col, int* __restrict__ cnt, int E) {
    int e = blockIdx.x * 256 + threadIdx.x;
    if (e < E) atomicAdd(&cnt[col[e]], 1);
}

// ---------------- scan stage 1: per-1024-block exclusive scan of PADDED counts ----------------
__global__ __launch_bounds__(256) void k_scan1(const int* __restrict__ cnt, int* __restrict__ excl,
                                               int* __restrict__ bsum, int n) {
    __shared__ int p[256];
    int base = blockIdx.x * 1024 + threadIdx.x * 4;
    int v0 = (base + 0 < n) ? ((cnt[base + 0] + 7) & ~7) : 0;
    int v1 = (base + 1 < n) ? ((cnt[base + 1] + 7) & ~7) : 0;
    int v2 = (base + 2 < n) ? ((cnt[base + 2] + 7) & ~7) : 0;
    int v3 = (base + 3 < n) ? ((cnt[base + 3] + 7) & ~7) : 0;
    int tsum = v0 + v1 + v2 + v3;
    p[threadIdx.x] = tsum;
    __syncthreads();
    for (int o = 1; o < 256; o <<= 1) {
        int t = (threadIdx.x >= o) ? p[threadIdx.x - o] : 0;
        __syncthreads();
        p[threadIdx.x] += t;
        __syncthreads();
    }
    int texcl = p[threadIdx.x] - tsum;
    if (base + 0 < n) excl[base + 0] = texcl;
    if (base + 1 < n) excl[base + 1] = texcl + v0;
    if (base + 2 < n) excl[base + 2] = texcl + v0 + v1;
    if (base + 3 < n) excl[base + 3] = texcl + v0 + v1 + v2;
    if (threadIdx.x == 255) bsum[blockIdx.x] = p[255];
}

// ---------------- scan stage 2 ----------------
__global__ __launch_bounds__(256) void k_scan2(int* __restrict__ bsum, int nb, int* __restrict__ totalOut) {
    __shared__ int p[256];
    int v = (threadIdx.x < nb) ? bsum[threadIdx.x] : 0;
    p[threadIdx.x] = v;
    __syncthreads();
    for (int o = 1; o < 256; o <<= 1) {
        int t = (threadIdx.x >= o) ? p[threadIdx.x - o] : 0;
        __syncthreads();
        p[threadIdx.x] += t;
        __syncthreads();
    }
    if (threadIdx.x == nb - 1) totalOut[0] = p[threadIdx.x];
    if (threadIdx.x < nb) bsum[threadIdx.x] = p[threadIdx.x] - v;
}

// ---------------- scan stage 3 ----------------
__global__ void k_scan3(int* __restrict__ rowptr, const int* __restrict__ bsum, int n) {
    int i = blockIdx.x * 256 + threadIdx.x;
    if (i < n) rowptr[i] += bsum[i >> 10];
}

// ---------------- CSR fill ----------------
__global__ void k_fill(const int* __restrict__ row, const int* __restrict__ col,
                       const float* __restrict__ w, const float* __restrict__ deg,
                       const int* __restrict__ rowptr, int* __restrict__ cursor,
                       float2* __restrict__ edata, int E) {
    int e = blockIdx.x * 256 + threadIdx.x;
    if (e >= E) return;
    int r = row[e];
    int c = col[e];
    float nm = rsqrtf(deg[r]) * w[e] * rsqrtf(deg[c]);
    int pos = rowptr[c] + atomicAdd(&cursor[c], 1);
    edata[pos] = make_float2(__int_as_float(r), nm);
}

// ---------------- tiled GEMM: 64 nodes x 64 dims per block, 4x4 register tile ----------------
// H2 = f(Hin) @ W ; f = identity or fused BN+ReLU (using stats of previous layer)
template<int K, bool FUSE_BN>
__global__ __launch_bounds__(256) void k_gemm_t(const float* __restrict__ Hin,
                                                const float* __restrict__ W,
                                                const float* __restrict__ stats,
                                                const float* __restrict__ g,
                                                const float* __restrict__ beta,
                                                float* __restrict__ H2, int n, float inv_n) {
    __shared__ float lX[64 * K];
    __shared__ float lW[K * 64];
    __shared__ float lmu[64], lsc[64], lbe[64];
    int tid = threadIdx.x;
    if (FUSE_BN) {
        if (tid < 64) {
            float mu  = stats[tid] * inv_n;
            float var = stats[64 + tid] * inv_n - mu * mu;
            lmu[tid] = mu;
            lsc[tid] = g[tid] * rsqrtf(var + BNEPS);
            lbe[tid] = beta[tid];
        }
        __syncthreads();
    }
    for (int idx = tid; idx < K * 64; idx += 256) lW[idx] = W[idx];
    int base = blockIdx.x * 64;
    for (int idx = tid; idx < 64 * K; idx += 256) {
        int nl = idx / K;
        int k  = idx - nl * K;
        int node = base + nl;
        float v = (node < n) ? Hin[(size_t)node * K + k] : 0.0f;
        if (FUSE_BN) v = fmaxf((v - lmu[k]) * lsc[k] + lbe[k], 0.0f);
        lX[idx] = v;
    }
    __syncthreads();

    int dq = tid & 15, nq = tid >> 4;
    int d0 = dq * 4, n0 = nq * 4;
    float acc[4][4];
    #pragma unroll
    for (int i = 0; i < 4; ++i)
        #pragma unroll
        for (int j = 0; j < 4; ++j) acc[i][j] = 0.0f;

    #pragma unroll 4
    for (int kb = 0; kb < K / 4; ++kb) {
        float4 wq[4];
        #pragma unroll
        for (int kk = 0; kk < 4; ++kk)
            wq[kk] = *(const float4*)&lW[(kb * 4 + kk) * 64 + d0];
        float4 xq[4];
        #pragma unroll
        for (int i = 0; i < 4; ++i)
            xq[i] = *(const float4*)&lX[(n0 + i) * K + kb * 4];
        #pragma unroll
        for (int i = 0; i < 4; ++i) {
            acc[i][0] = fmaf(xq[i].x, wq[0].x, acc[i][0]);
            acc[i][1] = fmaf(xq[i].x, wq[0].y, acc[i][1]);
            acc[i][2] = fmaf(xq[i].x, wq[0].z, acc[i][2]);
            acc[i][3] = fmaf(xq[i].x, wq[0].w, acc[i][3]);
            acc[i][0] = fmaf(xq[i].y, wq[1].x, acc[i][0]);
            acc[i][1] = fmaf(xq[i].y, wq[1].y, acc[i][1]);
            acc[i][2] = fmaf(xq[i].y, wq[1].z, acc[i][2]);
            acc[i][3] = fmaf(xq[i].y, wq[1].w, acc[i][3]);
            acc[i][0] = fmaf(xq[i].z, wq[2].x, acc[i][0]);
            acc[i][1] = fmaf(xq[i].z, wq[2].y, acc[i][1]);
            acc[i][2] = fmaf(xq[i].z, wq[2].z, acc[i][2]);
            acc[i][3] = fmaf(xq[i].z, wq[2].w, acc[i][3]);
            acc[i][0] = fmaf(xq[i].w, wq[3].x, acc[i][0]);
            acc[i][1] = fmaf(xq[i].w, wq[3].y, acc[i][1]);
            acc[i][2] = fmaf(xq[i].w, wq[3].z, acc[i][2]);
            acc[i][3] = fmaf(xq[i].w, wq[3].w, acc[i][3]);
        }
    }
    #pragma unroll
    for (int i = 0; i < 4; ++i) {
        int node = base + n0 + i;
        if (node < n)
            *(float4*)&H2[(size_t)node * 64 + d0] =
                make_float4(acc[i][0], acc[i][1], acc[i][2], acc[i][3]);
    }
}

// ---------------- gather aggregation: one wave per destination node, 8 edges/iter ----------------
__global__ __launch_bounds__(256) void k_gather(const int* __restrict__ rowptr,
                                                const float2* __restrict__ edata,
                                                const float* __restrict__ H,
                                                const float* __restrict__ b,
                                                const float* __restrict__ selfnorm,
                                                float* __restrict__ AGG, int n) {
    int node = (blockIdx.x * 256 + threadIdx.x) >> 6;
    int d = threadIdx.x & 63;
    if (node >= n) return;
    int s = rowptr[node], e = rowptr[node + 1];
    float acc = b[d] + selfnorm[node] * H[(size_t)node * 64 + d];
    for (int p = s; p < e; p += 8) {
        float4 q0 = *(const float4*)&edata[p];
        float4 q1 = *(const float4*)&edata[p + 2];
        float4 q2 = *(const float4*)&edata[p + 4];
        float4 q3 = *(const float4*)&edata[p + 6];
        float a0 = H[(size_t)__float_as_int(q0.x) * 64 + d];
        float a1 = H[(size_t)__float_as_int(q0.z) * 64 + d];
        float a2 = H[(size_t)__float_as_int(q1.x) * 64 + d];
        float a3 = H[(size_t)__float_as_int(q1.z) * 64 + d];
        float a4 = H[(size_t)__float_as_int(q2.x) * 64 + d];
        float a5 = H[(size_t)__float_as_int(q2.z) * 64 + d];
        float a6 = H[(size_t)__float_as_int(q3.x) * 64 + d];
        float a7 = H[(size_t)__float_as_int(q3.z) * 64 + d];
        acc = fmaf(q0.y, a0, acc);
        acc = fmaf(q0.w, a1, acc);
        acc = fmaf(q1.y, a2, acc);
        acc = fmaf(q1.w, a3, acc);
        acc = fmaf(q2.y, a4, acc);
        acc = fmaf(q2.w, a5, acc);
        acc = fmaf(q3.y, a6, acc);
        acc = fmaf(q3.w, a7, acc);
    }
    AGG[(size_t)node * 64 + d] = acc;
}

// ---------------- BN stats ----------------
__global__ __launch_bounds__(256) void k_stats(const float* __restrict__ AGG,
                                               float* __restrict__ stats, int n) {
    __shared__ float ls[256];
    __shared__ float lss[256];
    int d = threadIdx.x & 63, grp = threadIdx.x >> 6;
    float s = 0.0f, ss = 0.0f;
    for (int r = blockIdx.x * 4 + grp; r < n; r += gridDim.x * 4) {
        float v = AGG[(size_t)r * 64 + d];
        s += v;
        ss += v * v;
    }
    ls[threadIdx.x] = s;
    lss[threadIdx.x] = ss;
    __syncthreads();
    if (grp == 0) {
        s  = ls[d] + ls[64 + d] + ls[128 + d] + ls[192 + d];
        ss = lss[d] + lss[64 + d] + lss[128 + d] + lss[192 + d];
        atomicAdd(&stats[d], s);
        atomicAdd(&stats[64 + d], ss);
    }
}

// ---------------- BN apply + ReLU (final layer only) ----------------
__global__ __launch_bounds__(256) void k_bnapply(const float4* __restrict__ AGG4,
                                                 const float* __restrict__ stats,
                                                 const float* __restrict__ g,
                                                 const float* __restrict__ beta,
                                                 float4* __restrict__ out4,
                                                 int n, float inv_n) {
    size_t idx = (size_t)blockIdx.x * 256 + threadIdx.x;
    size_t total = (size_t)n * 16;
    if (idx >= total) return;
    int d0 = (int)((idx & 15) * 4);
    float4 v = AGG4[idx];
    float r[4] = {v.x, v.y, v.z, v.w};
    #pragma unroll
    for (int j = 0; j < 4; ++j) {
        int d = d0 + j;
        float mu  = stats[d] * inv_n;
        float var = stats[64 + d] * inv_n - mu * mu;
        float sc = g[d] * rsqrtf(var + BNEPS);
        r[j] = fmaxf((r[j] - mu) * sc + beta[d], 0.0f);
    }
    out4[idx] = make_float4(r[0], r[1], r[2], r[3]);
}

// ---------------- pool (mean by graph, batch sorted) + MLP head ----------------
__global__ __launch_bounds__(256) void k_pool_mlp(const float* __restrict__ H,
                                                  const int* __restrict__ batch, int n,
                                                  const float* __restrict__ Wp1,
                                                  const float* __restrict__ bp1,
                                                  const float* __restrict__ Wp2,
                                                  const float* __restrict__ bp2,
                                                  float* __restrict__ out) {
    int gidx = blockIdx.x;
    int lo = 0, hi = n;
    while (lo < hi) { int mid = (lo + hi) >> 1; if (batch[mid] < gidx) lo = mid + 1; else hi = mid; }
    int start = lo;
    lo = start; hi = n;
    while (lo < hi) { int mid = (lo + hi) >> 1; if (batch[mid] < gidx + 1) lo = mid + 1; else hi = mid; }
    int end = lo;

    int d = threadIdx.x & 63, grp = threadIdx.x >> 6;
    float s = 0.0f;
    for (int r = start + grp; r < end; r += 4) s += H[(size_t)r * 64 + d];
    __shared__ float ls[256];
    __shared__ float pooled[64];
    ls[threadIdx.x] = s;
    __syncthreads();
    if (grp == 0) {
        float cnt = (float)(end - start);
        float denom = fmaxf(cnt, 1.0f);
        pooled[d] = (ls[d] + ls[64 + d] + ls[128 + d] + ls[192 + d]) / denom;
    }
    __syncthreads();
    __shared__ float hidden[100];
    int j = threadIdx.x;
    if (j < 100) {
        float h = bp1[j];
        #pragma unroll 8
        for (int dd = 0; dd < 64; ++dd) h += pooled[dd] * Wp1[dd * 100 + j];
        hidden[j] = fmaxf(h, 0.0f);
    }
    __syncthreads();
    __shared__ float red[256];
    red[j] = (j < 100) ? hidden[j] * Wp2[j] : 0.0f;
    __syncthreads();
    for (int sft = 128; sft > 0; sft >>= 1) {
        if (j < sft) red[j] += red[j + sft];
        __syncthreads();
    }
    if (j == 0) out[gidx] = red[0] + bp2[0];
}

extern "C" void kernel_launch(void* const* d_in, const int* in_sizes, int n_in,
                              void* d_out, int out_size, void* d_ws, size_t ws_size,
                              hipStream_t stream) {
    const float* x    = (const float*)d_in[0];
    const int*   eidx = (const int*)d_in[1];
    const float* ew   = (const float*)d_in[2];
    const int*   batch= (const int*)d_in[3];
    const float* W0 = (const float*)d_in[4];  const float* b0 = (const float*)d_in[5];
    const float* g0 = (const float*)d_in[6];  const float* be0= (const float*)d_in[7];
    const float* W1 = (const float*)d_in[8];  const float* b1 = (const float*)d_in[9];
    const float* g1 = (const float*)d_in[10]; const float* be1= (const float*)d_in[11];
    const float* W2 = (const float*)d_in[12]; const float* b2 = (const float*)d_in[13];
    const float* g2 = (const float*)d_in[14]; const float* be2= (const float*)d_in[15];
    const float* Wp1= (const float*)d_in[16]; const float* bp1= (const float*)d_in[17];
    const float* Wp2= (const float*)d_in[18]; const float* bp2= (const float*)d_in[19];
    float* out = (float*)d_out;

    const int N = in_sizes[3];
    const int E = in_sizes[2];
    const int* row = eidx;          // sources
    const int* col = eidx + E;      // destinations

    size_t off = 0;
    auto alloc = [&](size_t bytes) {
        void* p = (char*)d_ws + off;
        off += (bytes + 255) & ~(size_t)255;
        return p;
    };
    const size_t EPAD = (size_t)E + 7 * (size_t)N;
    float*  deg      = (float*)alloc((size_t)N * 4);
    float*  selfnorm = (float*)alloc((size_t)N * 4);
    int*    cnt      = (int*)alloc((size_t)N * 4);
    int*    rowptr   = (int*)alloc((size_t)(N + 1) * 4);
    int*    bsum     = (int*)alloc(1024);
    float2* edata    = (float2*)alloc(EPAD * 8);
    float*  H2       = (float*)alloc((size_t)N * 64 * 4);
    float*  AGG      = (float*)alloc((size_t)N * 64 * 4);
    float*  H1       = (float*)alloc((size_t)N * 64 * 4);
    float*  stats    = (float*)alloc(512);
    (void)ws_size;

    const int TB = 256;
    const int gN    = (N + TB - 1) / TB;
    const int gE    = (E + TB - 1) / TB;
    const int gNd4  = (N * 16 + TB - 1) / TB;
    const int gGemm = (N + 63) / 64;
    const int gGath = (N + 3) / 4;
    const int nbScan = (N + 1023) / 1024;
    const float inv_n = 1.0f / (float)N;

    // ---- gcn_norm + padded CSR build ----
    k_init_deg<<<gN, TB, 0, stream>>>(deg, N);
    k_deg_scatter<<<gE, TB, 0, stream>>>(col, ew, deg, E);
    k_selfnorm<<<gN, TB, 0, stream>>>(deg, selfnorm, N);

    hipMemsetAsync(cnt, 0, (size_t)N * 4, stream);
    k_hist<<<gE, TB, 0, stream>>>(col, cnt, E);
    k_scan1<<<nbScan, TB, 0, stream>>>(cnt, rowptr, bsum, N);
    k_scan2<<<1, TB, 0, stream>>>(bsum, nbScan, rowptr + N);
    k_scan3<<<gN, TB, 0, stream>>>(rowptr, bsum, N);
    hipMemsetAsync(cnt, 0, (size_t)N * 4, stream);
    hipMemsetAsync(edata, 0, EPAD * 8, stream);
    k_fill<<<gE, TB, 0, stream>>>(row, col, ew, deg, rowptr, cnt, edata, E);

    // ---- layer 0 ----
    k_gemm_t<92, false><<<gGemm, TB, 0, stream>>>(x, W0, nullptr, nullptr, nullptr, H2, N, inv_n);
    k_gather<<<gGath, TB, 0, stream>>>(rowptr, edata, H2, b0, selfnorm, AGG, N);
    hipMemsetAsync(stats, 0, 512, stream);
    k_stats<<<256, TB, 0, stream>>>(AGG, stats, N);

    // ---- layer 1 (BN0+ReLU fused into GEMM staging) ----
    k_gemm_t<64, true><<<gGemm, TB, 0, stream>>>(AGG, W1, stats, g0, be0, H2, N, inv_n);
    k_gather<<<gGath, TB, 0, stream>>>(rowptr, edata, H2, b1, selfnorm, AGG, N);
    hipMemsetAsync(stats, 0, 512, stream);
    k_stats<<<256, TB, 0, stream>>>(AGG, stats, N);

    // ---- layer 2 (BN1+ReLU fused into GEMM staging) ----
    k_gemm_t<64, true><<<gGemm, TB, 0, stream>>>(AGG, W2, stats, g1, be1, H2, N, inv_n);
    k_gather<<<gGath, TB, 0, stream>>>(rowptr, edata, H2, b2, selfnorm, AGG, N);
    hipMemsetAsync(stats, 0, 512, stream);
    k_stats<<<256, TB, 0, stream>>>(AGG, stats, N);

    // ---- final BN + ReLU, pool + MLP head ----
    k_bnapply<<<gNd4, TB, 0, stream>>>((const float4*)AGG, stats, g2, be2, (float4*)H1, N, inv_n);
    k_pool_mlp<<<NGRAPH, TB, 0, stream>>>(H1, batch, N, Wp1, bp1, Wp2, bp2, out);

    (void)n_in; (void)out_size;
}